// Round 1
// baseline (344.003 us; speedup 1.0000x reference)
//
#include <hip/hip_runtime.h>

// EdgewiseEnergySum:
//   out[n] = 0.125 * sum_{e : center(e)==n} edge_eng[e] * scales[sp[center(e)], sp[neighbor(e)]]
//
// Inputs (setup_inputs order):
//   d_in[0] = edge_eng        float32 [6400000]
//   d_in[1] = edge_index      int32   [2, 6400000]   (harness converts integer inputs to int32)
//   d_in[2] = species         int32   [100000]
//   d_in[3] = per_edge_scales float32 [4,4]
// Output: float32 [100000]

__global__ void edgewise_energy_sum_kernel(const float* __restrict__ edge_eng,
                                           const int*   __restrict__ edge_center,
                                           const int*   __restrict__ edge_neighbor,
                                           const int*   __restrict__ species,
                                           const float* __restrict__ scales,
                                           float*       __restrict__ out,
                                           int n_edges)
{
    // Cache the 4x4 scale table in LDS, pre-multiplied by 1/sqrt(64) = 0.125.
    __shared__ float s_scale[16];
    if (threadIdx.x < 16) s_scale[threadIdx.x] = scales[threadIdx.x] * 0.125f;
    __syncthreads();

    const int n4     = n_edges >> 2;           // groups of 4 edges
    const int stride = gridDim.x * blockDim.x;

    for (int g = blockIdx.x * blockDim.x + threadIdx.x; g < n4; g += stride) {
        const int4   c  = ((const int4*)  edge_center  )[g];
        const int4   nb = ((const int4*)  edge_neighbor)[g];
        const float4 e  = ((const float4*)edge_eng     )[g];

        {
            const int cs = species[c.x], ns = species[nb.x];
            atomicAdd(&out[c.x], e.x * s_scale[(cs << 2) | ns]);
        }
        {
            const int cs = species[c.y], ns = species[nb.y];
            atomicAdd(&out[c.y], e.y * s_scale[(cs << 2) | ns]);
        }
        {
            const int cs = species[c.z], ns = species[nb.z];
            atomicAdd(&out[c.z], e.z * s_scale[(cs << 2) | ns]);
        }
        {
            const int cs = species[c.w], ns = species[nb.w];
            atomicAdd(&out[c.w], e.w * s_scale[(cs << 2) | ns]);
        }
    }

    // Tail (n_edges not divisible by 4) — not hit for 6.4M edges, kept for safety.
    const int tail_start = n4 << 2;
    for (int i = tail_start + blockIdx.x * blockDim.x + threadIdx.x; i < n_edges; i += stride) {
        const int cen = edge_center[i];
        const int cs  = species[cen];
        const int ns  = species[edge_neighbor[i]];
        atomicAdd(&out[cen], edge_eng[i] * s_scale[(cs << 2) | ns]);
    }
}

extern "C" void kernel_launch(void* const* d_in, const int* in_sizes, int n_in,
                              void* d_out, int out_size, void* d_ws, size_t ws_size,
                              hipStream_t stream) {
    const float* edge_eng   = (const float*)d_in[0];
    const int*   edge_index = (const int*)  d_in[1];
    const int*   species    = (const int*)  d_in[2];
    const float* scales     = (const float*)d_in[3];
    float*       out        = (float*)      d_out;

    const int n_edges = in_sizes[1] / 2;            // edge_index is [2, N_EDGES]
    const int* edge_center   = edge_index;
    const int* edge_neighbor = edge_index + n_edges;

    // Output is poisoned (0xAA) before timing and never re-zeroed between
    // replays — zero it every launch so the atomic accumulation is correct.
    hipMemsetAsync(d_out, 0, (size_t)out_size * sizeof(float), stream);

    const int block = 256;
    int grid = (n_edges / 4 + block - 1) / block;
    if (grid > 2048) grid = 2048;                   // grid-stride covers the rest
    edgewise_energy_sum_kernel<<<grid, block, 0, stream>>>(
        edge_eng, edge_center, edge_neighbor, species, scales, out, n_edges);
}

// Round 2
// 161.690 us; speedup vs baseline: 2.1276x; 2.1276x over previous
//
#include <hip/hip_runtime.h>

// EdgewiseEnergySum:
//   out[n] = 0.125 * sum_{e : center(e)==n} edge_eng[e] * scales[sp[center(e)], sp[neighbor(e)]]
//
// Round-1 lesson: 6.4M device-scope fp32 atomics ran at ~18.6 G/s
// (WRITE_SIZE = 199.6 MB = 6.4M x 32B memory-side transactions) -> 344 us.
// Round-2 structure: counting-sort into 98 node-buckets (node>>10), then
// LDS-accumulate per bucket. Global atomics drop to ~50K (range allocation).
//
// Inputs (setup_inputs order):
//   d_in[0] = edge_eng        float32 [6400000]
//   d_in[1] = edge_index      int32   [2, 6400000]
//   d_in[2] = species         int32   [100000]
//   d_in[3] = per_edge_scales float32 [4,4]
// Output: float32 [100000]

#define BUCKET_SHIFT 10
#define BUCKET_NODES 1024            // nodes per bucket
#define MAX_NB       128             // LDS sizing; actual NB = 98 for 100K nodes
#define CAP          73728           // per-bucket edge capacity (E=65536, +32 sigma)
#define SPLIT        8               // K2 blocks per bucket
#define K1_BLOCKS    512

// ---------------- K1: histogram + range-alloc + scatter -------------------
__global__ void k1_scatter(const float* __restrict__ edge_eng,
                           const int*   __restrict__ edge_center,
                           const int*   __restrict__ edge_neighbor,
                           const int*   __restrict__ species,
                           const float* __restrict__ scales,
                           int2*        __restrict__ pairs,     // [NB][CAP]
                           int*         __restrict__ counters,  // [NB], pre-zeroed
                           int n_edges, int nb)
{
    __shared__ float s_scale[16];
    __shared__ int hist[MAX_NB];
    __shared__ int base[MAX_NB];
    __shared__ int cursor[MAX_NB];

    const int tid = threadIdx.x;
    if (tid < 16) s_scale[tid] = scales[tid] * 0.125f;   // fold 1/sqrt(64)
    for (int b = tid; b < nb; b += blockDim.x) hist[b] = 0;
    __syncthreads();

    const int chunk = (n_edges + gridDim.x - 1) / gridDim.x;
    const int lo = blockIdx.x * chunk;
    const int hi = min(lo + chunk, n_edges);

    // Phase A: per-block histogram of bucket ids (chunk stays L2-hot for phase C)
    for (int i = lo + tid; i < hi; i += blockDim.x)
        atomicAdd(&hist[edge_center[i] >> BUCKET_SHIFT], 1);
    __syncthreads();

    // Phase B: one global atomic per (block,bucket) to reserve a contiguous range
    for (int b = tid; b < nb; b += blockDim.x) {
        const int c = hist[b];
        base[b]   = c ? atomicAdd(&counters[b], c) : 0;
        cursor[b] = 0;
    }
    __syncthreads();

    // Phase C: scatter (center, scaled value) pairs into reserved ranges.
    // Writes within a (block,bucket) range are sequential -> L2 write-combining.
    for (int i = lo + tid; i < hi; i += blockDim.x) {
        const int c  = edge_center[i];
        const int b  = c >> BUCKET_SHIFT;
        const int cs = species[c];
        const int ns = species[edge_neighbor[i]];
        const float v = edge_eng[i] * s_scale[(cs << 2) | ns];
        const int r   = atomicAdd(&cursor[b], 1);        // LDS atomic
        const int pos = base[b] + r;
        if (pos < CAP)                                   // statistical impossibility; memory safety
            pairs[(size_t)b * CAP + pos] = make_int2(c, __float_as_int(v));
    }
}

// ---------------- K2: per-bucket LDS accumulation -------------------------
__global__ void k2_accumulate(const int2* __restrict__ pairs,
                              const int*  __restrict__ counters,
                              float*      __restrict__ partials) // [NB][SPLIT][1024]
{
    __shared__ float acc[BUCKET_NODES];
    const int b   = blockIdx.x / SPLIT;
    const int s   = blockIdx.x % SPLIT;
    const int tid = threadIdx.x;

    for (int i = tid; i < BUCKET_NODES; i += blockDim.x) acc[i] = 0.0f;
    __syncthreads();

    const int count = min(counters[b], CAP);
    const int lo = (int)((long long)count * s / SPLIT);
    const int hi = (int)((long long)count * (s + 1) / SPLIT);
    const int2* p = pairs + (size_t)b * CAP;

    for (int i = lo + tid; i < hi; i += blockDim.x) {
        const int2 e = p[i];
        atomicAdd(&acc[e.x & (BUCKET_NODES - 1)], __int_as_float(e.y));  // LDS atomic
    }
    __syncthreads();

    float* dst = partials + ((size_t)b * SPLIT + s) * BUCKET_NODES;
    for (int i = tid; i < BUCKET_NODES; i += blockDim.x) dst[i] = acc[i];
}

// ---------------- K3: reduce SPLIT partials, plain store ------------------
__global__ void k3_reduce(const float* __restrict__ partials,
                          float*       __restrict__ out, int n_nodes)
{
    const int n = blockIdx.x * blockDim.x + threadIdx.x;
    if (n >= n_nodes) return;
    const int b     = n >> BUCKET_SHIFT;
    const int local = n & (BUCKET_NODES - 1);
    const float* p  = partials + (size_t)b * SPLIT * BUCKET_NODES + local;
    float sum = 0.0f;
#pragma unroll
    for (int i = 0; i < SPLIT; ++i) sum += p[i * BUCKET_NODES];
    out[n] = sum;
}

// ---------------- Fallback: round-1 atomic kernel (if ws too small) -------
__global__ void fallback_atomic_kernel(const float* __restrict__ edge_eng,
                                       const int*   __restrict__ edge_center,
                                       const int*   __restrict__ edge_neighbor,
                                       const int*   __restrict__ species,
                                       const float* __restrict__ scales,
                                       float*       __restrict__ out, int n_edges)
{
    __shared__ float s_scale[16];
    if (threadIdx.x < 16) s_scale[threadIdx.x] = scales[threadIdx.x] * 0.125f;
    __syncthreads();
    const int stride = gridDim.x * blockDim.x;
    for (int i = blockIdx.x * blockDim.x + threadIdx.x; i < n_edges; i += stride) {
        const int c  = edge_center[i];
        const int cs = species[c];
        const int ns = species[edge_neighbor[i]];
        atomicAdd(&out[c], edge_eng[i] * s_scale[(cs << 2) | ns]);
    }
}

extern "C" void kernel_launch(void* const* d_in, const int* in_sizes, int n_in,
                              void* d_out, int out_size, void* d_ws, size_t ws_size,
                              hipStream_t stream) {
    const float* edge_eng   = (const float*)d_in[0];
    const int*   edge_index = (const int*)  d_in[1];
    const int*   species    = (const int*)  d_in[2];
    const float* scales     = (const float*)d_in[3];
    float*       out        = (float*)      d_out;

    const int n_edges = in_sizes[1] / 2;
    const int n_nodes = in_sizes[2];
    const int* edge_center   = edge_index;
    const int* edge_neighbor = edge_index + n_edges;

    const int nb = (n_nodes + BUCKET_NODES - 1) >> BUCKET_SHIFT;

    // Workspace layout: [counters: 4096 B pad][pairs: NB*CAP*8][partials: NB*SPLIT*1024*4]
    const size_t off_counters = 0;
    const size_t off_pairs    = 4096;
    const size_t off_partials = off_pairs + (size_t)nb * CAP * sizeof(int2);
    const size_t needed       = off_partials + (size_t)nb * SPLIT * BUCKET_NODES * sizeof(float);

    if (nb > MAX_NB || ws_size < needed) {
        // Correct-but-slow fallback (round-1 path).
        hipMemsetAsync(d_out, 0, (size_t)out_size * sizeof(float), stream);
        int grid = (n_edges + 255) / 256;
        if (grid > 2048) grid = 2048;
        fallback_atomic_kernel<<<grid, 256, 0, stream>>>(
            edge_eng, edge_center, edge_neighbor, species, scales, out, n_edges);
        return;
    }

    int*   counters = (int*)  ((char*)d_ws + off_counters);
    int2*  pairs    = (int2*) ((char*)d_ws + off_pairs);
    float* partials = (float*)((char*)d_ws + off_partials);

    hipMemsetAsync(counters, 0, (size_t)nb * sizeof(int), stream);

    k1_scatter<<<K1_BLOCKS, 256, 0, stream>>>(
        edge_eng, edge_center, edge_neighbor, species, scales,
        pairs, counters, n_edges, nb);

    k2_accumulate<<<nb * SPLIT, 256, 0, stream>>>(pairs, counters, partials);

    k3_reduce<<<(n_nodes + 255) / 256, 256, 0, stream>>>(partials, out, n_nodes);
}

// Round 3
// 120.405 us; speedup vs baseline: 2.8571x; 1.3429x over previous
//
#include <hip/hip_runtime.h>

// EdgewiseEnergySum:
//   out[n] = 0.125 * sum_{e : center(e)==n} edge_eng[e] * scales[sp[center(e)], sp[neighbor(e)]]
//
// Round-1: 6.4M device-scope atomics -> 344 us (memory-side atomic throttle).
// Round-2: bucket counting-sort -> 162 us, but K1 latency-bound (occ 21%,
//          VALU 3%, HBM 10%): random species gathers + low occupancy.
// Round-3: (a) species packed 2-bit -> 25 KB LDS table (kills 12.8M random
//          global gathers), (b) int4/float4 vector edge loads (4x ILP),
//          (c) 1024 blocks for ~50% occupancy.

#define BUCKET_SHIFT 10
#define BUCKET_NODES 1024
#define MAX_NB       128
#define CAP          73728            // 65536 mean + ~32 sigma
#define SPLIT        8
#define K1_BLOCKS    1024
#define MAX_SP_WORDS 6272             // 16 species/word -> up to 100352 nodes, 25 KB LDS

// ---------------- K0: pack species (2 bits each) --------------------------
__global__ void k0_pack(const int* __restrict__ species,
                        unsigned int* __restrict__ packed,
                        int n_nodes, int n_words)
{
    const int w = blockIdx.x * blockDim.x + threadIdx.x;
    if (w >= n_words) return;
    const int base = w * 16;
    const int m = min(16, n_nodes - base);
    unsigned int v = 0;
    for (int j = 0; j < m; ++j)
        v |= (unsigned int)(species[base + j] & 3) << (2 * j);
    packed[w] = v;
}

// ---------------- K1: histogram + range-alloc + scatter -------------------
__global__ void __launch_bounds__(256, 4)
k1_scatter(const float* __restrict__ edge_eng,
           const int*   __restrict__ edge_center,
           const int*   __restrict__ edge_neighbor,
           const unsigned int* __restrict__ sp_packed,
           const float* __restrict__ scales,
           int2*        __restrict__ pairs,     // [NB][CAP]
           int*         __restrict__ counters,  // [NB], pre-zeroed
           int n_edges, int nb, int n_sp_words)
{
    __shared__ unsigned int s_sp[MAX_SP_WORDS];  // 25 KB packed species
    __shared__ float s_scale[16];
    __shared__ int hist[MAX_NB];
    __shared__ int rbase[MAX_NB];
    __shared__ int cursor[MAX_NB];

    const int tid = threadIdx.x;
    if (tid < 16) s_scale[tid] = scales[tid] * 0.125f;   // fold 1/sqrt(64)
    for (int i = tid; i < n_sp_words; i += blockDim.x) s_sp[i] = sp_packed[i];
    for (int b = tid; b < nb; b += blockDim.x) hist[b] = 0;
    __syncthreads();

    // chunk: multiple of 4 so vector loads stay 16B-aligned
    const int chunk = (((n_edges + gridDim.x - 1) / gridDim.x + 3) >> 2) << 2;
    const int lo = blockIdx.x * chunk;
    const int hi = min(lo + chunk, n_edges);
    const bool vec_ok = ((n_edges & 3) == 0);   // neighbor ptr alignment

    // Phase A: bucket histogram (vectorized center reads)
    if (vec_ok) {
        for (int i = lo + (tid << 2); i < hi; i += (blockDim.x << 2)) {
            if (i + 3 < hi) {
                const int4 c = *(const int4*)(edge_center + i);
                atomicAdd(&hist[c.x >> BUCKET_SHIFT], 1);
                atomicAdd(&hist[c.y >> BUCKET_SHIFT], 1);
                atomicAdd(&hist[c.z >> BUCKET_SHIFT], 1);
                atomicAdd(&hist[c.w >> BUCKET_SHIFT], 1);
            } else {
                for (int j = i; j < hi; ++j)
                    atomicAdd(&hist[edge_center[j] >> BUCKET_SHIFT], 1);
            }
        }
    } else {
        for (int i = lo + tid; i < hi; i += blockDim.x)
            atomicAdd(&hist[edge_center[i] >> BUCKET_SHIFT], 1);
    }
    __syncthreads();

    // Phase B: reserve contiguous per-(block,bucket) ranges
    for (int b = tid; b < nb; b += blockDim.x) {
        const int c = hist[b];
        rbase[b]  = c ? atomicAdd(&counters[b], c) : 0;
        cursor[b] = 0;
    }
    __syncthreads();

    // Phase C: scatter (center, scaled value); species from LDS
#define SP(n) ((s_sp[(n) >> 4] >> (((n) & 15) << 1)) & 3)
#define EDGE_BODY(cc, nn, ee)                                              \
    {                                                                      \
        const int b_ = (cc) >> BUCKET_SHIFT;                               \
        const float v_ = (ee) * s_scale[(SP(cc) << 2) | SP(nn)];           \
        const int r_ = atomicAdd(&cursor[b_], 1);                          \
        const int pos_ = rbase[b_] + r_;                                   \
        if (pos_ < CAP)                                                    \
            pairs[(size_t)b_ * CAP + pos_] = make_int2((cc), __float_as_int(v_)); \
    }

    if (vec_ok) {
        for (int i = lo + (tid << 2); i < hi; i += (blockDim.x << 2)) {
            if (i + 3 < hi) {
                const int4   c  = *(const int4*)  (edge_center   + i);
                const int4   nb4= *(const int4*)  (edge_neighbor + i);
                const float4 e  = *(const float4*)(edge_eng      + i);
                EDGE_BODY(c.x, nb4.x, e.x);
                EDGE_BODY(c.y, nb4.y, e.y);
                EDGE_BODY(c.z, nb4.z, e.z);
                EDGE_BODY(c.w, nb4.w, e.w);
            } else {
                for (int j = i; j < hi; ++j)
                    EDGE_BODY(edge_center[j], edge_neighbor[j], edge_eng[j]);
            }
        }
    } else {
        for (int i = lo + tid; i < hi; i += blockDim.x)
            EDGE_BODY(edge_center[i], edge_neighbor[i], edge_eng[i]);
    }
#undef EDGE_BODY
#undef SP
}

// ---------------- K2: per-bucket LDS accumulation -------------------------
__global__ void k2_accumulate(const int2* __restrict__ pairs,
                              const int*  __restrict__ counters,
                              float*      __restrict__ partials) // [NB][SPLIT][1024]
{
    __shared__ float acc[BUCKET_NODES];
    const int b   = blockIdx.x / SPLIT;
    const int s   = blockIdx.x % SPLIT;
    const int tid = threadIdx.x;

    for (int i = tid; i < BUCKET_NODES; i += blockDim.x) acc[i] = 0.0f;
    __syncthreads();

    const int count = min(counters[b], CAP);
    const int lo = (int)((long long)count * s / SPLIT);
    const int hi = (int)((long long)count * (s + 1) / SPLIT);
    const int2* p = pairs + (size_t)b * CAP;

    for (int i = lo + tid; i < hi; i += blockDim.x) {
        const int2 e = p[i];
        atomicAdd(&acc[e.x & (BUCKET_NODES - 1)], __int_as_float(e.y));
    }
    __syncthreads();

    float* dst = partials + ((size_t)b * SPLIT + s) * BUCKET_NODES;
    for (int i = tid; i < BUCKET_NODES; i += blockDim.x) dst[i] = acc[i];
}

// ---------------- K3: reduce SPLIT partials, plain store ------------------
__global__ void k3_reduce(const float* __restrict__ partials,
                          float*       __restrict__ out, int n_nodes)
{
    const int n = blockIdx.x * blockDim.x + threadIdx.x;
    if (n >= n_nodes) return;
    const int b     = n >> BUCKET_SHIFT;
    const int local = n & (BUCKET_NODES - 1);
    const float* p  = partials + (size_t)b * SPLIT * BUCKET_NODES + local;
    float sum = 0.0f;
#pragma unroll
    for (int i = 0; i < SPLIT; ++i) sum += p[i * BUCKET_NODES];
    out[n] = sum;
}

// ---------------- Fallback: atomic kernel (if ws too small) ---------------
__global__ void fallback_atomic_kernel(const float* __restrict__ edge_eng,
                                       const int*   __restrict__ edge_center,
                                       const int*   __restrict__ edge_neighbor,
                                       const int*   __restrict__ species,
                                       const float* __restrict__ scales,
                                       float*       __restrict__ out, int n_edges)
{
    __shared__ float s_scale[16];
    if (threadIdx.x < 16) s_scale[threadIdx.x] = scales[threadIdx.x] * 0.125f;
    __syncthreads();
    const int stride = gridDim.x * blockDim.x;
    for (int i = blockIdx.x * blockDim.x + threadIdx.x; i < n_edges; i += stride) {
        const int c  = edge_center[i];
        const int cs = species[c];
        const int ns = species[edge_neighbor[i]];
        atomicAdd(&out[c], edge_eng[i] * s_scale[(cs << 2) | ns]);
    }
}

extern "C" void kernel_launch(void* const* d_in, const int* in_sizes, int n_in,
                              void* d_out, int out_size, void* d_ws, size_t ws_size,
                              hipStream_t stream) {
    const float* edge_eng   = (const float*)d_in[0];
    const int*   edge_index = (const int*)  d_in[1];
    const int*   species    = (const int*)  d_in[2];
    const float* scales     = (const float*)d_in[3];
    float*       out        = (float*)      d_out;

    const int n_edges = in_sizes[1] / 2;
    const int n_nodes = in_sizes[2];
    const int* edge_center   = edge_index;
    const int* edge_neighbor = edge_index + n_edges;

    const int nb       = (n_nodes + BUCKET_NODES - 1) >> BUCKET_SHIFT;
    const int n_words  = (n_nodes + 15) / 16;

    // ws layout: [counters pad 4096][packed species][pairs][partials]
    const size_t off_counters = 0;
    const size_t off_packed   = 4096;
    const size_t off_pairs    = off_packed + ((size_t)n_words * 4 + 255 & ~(size_t)255);
    const size_t off_partials = off_pairs + (size_t)nb * CAP * sizeof(int2);
    const size_t needed       = off_partials + (size_t)nb * SPLIT * BUCKET_NODES * sizeof(float);

    if (nb > MAX_NB || n_words > MAX_SP_WORDS || ws_size < needed) {
        hipMemsetAsync(d_out, 0, (size_t)out_size * sizeof(float), stream);
        int grid = (n_edges + 255) / 256;
        if (grid > 2048) grid = 2048;
        fallback_atomic_kernel<<<grid, 256, 0, stream>>>(
            edge_eng, edge_center, edge_neighbor, species, scales, out, n_edges);
        return;
    }

    int*          counters = (int*)         ((char*)d_ws + off_counters);
    unsigned int* packed   = (unsigned int*)((char*)d_ws + off_packed);
    int2*         pairs    = (int2*)        ((char*)d_ws + off_pairs);
    float*        partials = (float*)       ((char*)d_ws + off_partials);

    hipMemsetAsync(counters, 0, (size_t)nb * sizeof(int), stream);

    k0_pack<<<(n_words + 255) / 256, 256, 0, stream>>>(species, packed, n_nodes, n_words);

    k1_scatter<<<K1_BLOCKS, 256, 0, stream>>>(
        edge_eng, edge_center, edge_neighbor, packed, scales,
        pairs, counters, n_edges, nb, n_words);

    k2_accumulate<<<nb * SPLIT, 256, 0, stream>>>(pairs, counters, partials);

    k3_reduce<<<(n_nodes + 255) / 256, 256, 0, stream>>>(partials, out, n_nodes);
}

// Round 6
// 119.444 us; speedup vs baseline: 2.8800x; 1.0080x over previous
//
#include <hip/hip_runtime.h>

// EdgewiseEnergySum:
//   out[n] = 0.125 * sum_{e : center(e)==n} edge_eng[e] * scales[sp[center(e)], sp[neighbor(e)]]
//
// R1: 6.4M device atomics -> 344 us (memory-side atomic throttle, 32B/atomic).
// R2: bucket counting-sort -> 162 us (K1 latency-bound, occ 21%).
// R3: species 2-bit LDS table + int4 loads + 1024 blocks -> 120 us (K1 95 us,
//     occ 37%, VALU 6%, HBM 18% -> still latency-bound; edges read twice).
// R4: K1 single-pass: 16 edges/thread held in REGISTERS (load once, histogram
//     from regs, scatter from regs -> phase C has no load latency); global
//     counters striped x8 (phase-B serialization /8); counter-zero folded
//     into k0.  (Rounds 4-5 died to an unresponsive container; resubmit.)

#define BUCKET_SHIFT 10
#define BUCKET_NODES 1024
#define MAX_NB       128
#define NSTRIPE      8
#define CAP8         8960             // per-(bucket,stripe): mean 8192 + ~8 sigma
#define T_EDGES      16               // edges per thread
#define CHUNK        4096             // 256 threads * 16 edges
#define MAX_SP_WORDS 6272             // 2-bit species, 16/word: up to 100352 nodes (25 KB)

// ---------------- K0: pack species 2-bit + zero counters ------------------
__global__ void k0_pack(const int* __restrict__ species,
                        unsigned int* __restrict__ packed,
                        int* __restrict__ counters,
                        int n_nodes, int n_words, int n_cnt)
{
    const int w = blockIdx.x * blockDim.x + threadIdx.x;
    if (w < n_cnt) counters[w] = 0;
    if (w >= n_words) return;
    const int base = w * 16;
    unsigned int v = 0;
    if (base + 16 <= n_nodes) {
#pragma unroll
        for (int q = 0; q < 4; ++q) {
            const int4 s4 = *(const int4*)(species + base + 4 * q);
            v |= (unsigned int)(s4.x & 3) << (8 * q + 0);
            v |= (unsigned int)(s4.y & 3) << (8 * q + 2);
            v |= (unsigned int)(s4.z & 3) << (8 * q + 4);
            v |= (unsigned int)(s4.w & 3) << (8 * q + 6);
        }
    } else {
        const int m = n_nodes - base;
        for (int j = 0; j < m; ++j)
            v |= (unsigned int)(species[base + j] & 3) << (2 * j);
    }
    packed[w] = v;
}

// ---------------- K1: reg-resident histogram + alloc + scatter ------------
__global__ void __launch_bounds__(256)
k1_scatter(const float* __restrict__ edge_eng,
           const int*   __restrict__ edge_center,
           const int*   __restrict__ edge_neighbor,
           const unsigned int* __restrict__ sp_packed,
           const float* __restrict__ scales,
           int2*        __restrict__ pairs,     // [NB*NSTRIPE][CAP8]
           int*         __restrict__ counters,  // [NB*NSTRIPE], zeroed by k0
           int n_edges, int nb, int n_sp_words)
{
    __shared__ unsigned int s_sp[MAX_SP_WORDS];
    __shared__ float s_scale[16];
    __shared__ int hist[MAX_NB];
    __shared__ int rbase[MAX_NB];
    __shared__ int cursor[MAX_NB];

    const int tid = threadIdx.x;
    if (tid < 16) s_scale[tid] = scales[tid] * 0.125f;   // fold 1/sqrt(64)
    for (int i = tid; i < n_sp_words; i += blockDim.x) s_sp[i] = sp_packed[i];
    for (int b = tid; b < nb; b += blockDim.x) hist[b] = 0;
    __syncthreads();

    const int lo     = blockIdx.x * CHUNK;
    const int stripe = blockIdx.x & (NSTRIPE - 1);

    // ---- Load this thread's 16 edges ONCE into registers -----------------
    int4   c4[4];
    int4   n4[4];
    float4 e4[4];
    const bool full = ((n_edges & 3) == 0) && (lo + CHUNK <= n_edges);
    if (full) {
#pragma unroll
        for (int k = 0; k < 4; ++k) {
            const int idx = lo + 4 * tid + 1024 * k;
            c4[k] = *(const int4*)  (edge_center   + idx);
            n4[k] = *(const int4*)  (edge_neighbor + idx);
            e4[k] = *(const float4*)(edge_eng      + idx);
        }
    } else {
#pragma unroll
        for (int k = 0; k < 4; ++k) {
            const int idx = lo + 4 * tid + 1024 * k;
            int*   cp = (int*)  &c4[k];
            int*   np = (int*)  &n4[k];
            float* ep = (float*)&e4[k];
#pragma unroll
            for (int j = 0; j < 4; ++j) {
                const int i = idx + j;
                if (i < n_edges) { cp[j] = edge_center[i]; np[j] = edge_neighbor[i]; ep[j] = edge_eng[i]; }
                else             { cp[j] = -1; np[j] = 0; ep[j] = 0.0f; }
            }
        }
    }

    // ---- Phase A: histogram from registers -------------------------------
#pragma unroll
    for (int k = 0; k < 4; ++k) {
        const int* cp = (const int*)&c4[k];
#pragma unroll
        for (int j = 0; j < 4; ++j)
            if (cp[j] >= 0) atomicAdd(&hist[cp[j] >> BUCKET_SHIFT], 1);
    }
    __syncthreads();

    // ---- Phase B: reserve ranges in this block's stripe ------------------
    for (int b = tid; b < nb; b += blockDim.x) {
        const int c = hist[b];
        rbase[b]  = c ? atomicAdd(&counters[(b << 3) | stripe], c) : 0;
        cursor[b] = 0;
    }
    __syncthreads();

    // ---- Phase C: scatter from registers (no global loads) ---------------
#define SP(n) ((s_sp[(unsigned)(n) >> 4] >> (((n) & 15) << 1)) & 3)
#pragma unroll
    for (int k = 0; k < 4; ++k) {
        const int*   cp = (const int*)  &c4[k];
        const int*   np = (const int*)  &n4[k];
        const float* ep = (const float*)&e4[k];
#pragma unroll
        for (int j = 0; j < 4; ++j) {
            const int c = cp[j];
            if (c < 0) continue;
            const int   b = c >> BUCKET_SHIFT;
            const float v = ep[j] * s_scale[(SP(c) << 2) | SP(np[j])];
            const int   r = atomicAdd(&cursor[b], 1);         // LDS atomic
            const int pos = rbase[b] + r;
            if (pos < CAP8)                                    // ~8-sigma guard
                pairs[(size_t)((b << 3) | stripe) * CAP8 + pos] =
                    make_int2(c, __float_as_int(v));
        }
    }
#undef SP
}

// ---------------- K2: per-(bucket,stripe) LDS accumulation ----------------
__global__ void k2_accumulate(const int2* __restrict__ pairs,
                              const int*  __restrict__ counters,
                              float*      __restrict__ partials) // [NB*NSTRIPE][1024]
{
    __shared__ float acc[BUCKET_NODES];
    const int bs  = blockIdx.x;                // (b<<3)|s
    const int tid = threadIdx.x;

    for (int i = tid; i < BUCKET_NODES; i += blockDim.x) acc[i] = 0.0f;
    __syncthreads();

    const int count = min(counters[bs], CAP8);
    const int2* p = pairs + (size_t)bs * CAP8;

    for (int i = tid; i < count; i += blockDim.x) {
        const int2 e = p[i];
        atomicAdd(&acc[e.x & (BUCKET_NODES - 1)], __int_as_float(e.y));
    }
    __syncthreads();

    float* dst = partials + (size_t)bs * BUCKET_NODES;
    for (int i = tid; i < BUCKET_NODES; i += blockDim.x) dst[i] = acc[i];
}

// ---------------- K3: reduce NSTRIPE partials, plain store ----------------
__global__ void k3_reduce(const float* __restrict__ partials,
                          float*       __restrict__ out, int n_nodes)
{
    const int n = blockIdx.x * blockDim.x + threadIdx.x;
    if (n >= n_nodes) return;
    const int b     = n >> BUCKET_SHIFT;
    const int local = n & (BUCKET_NODES - 1);
    const float* p  = partials + (size_t)b * NSTRIPE * BUCKET_NODES + local;
    float sum = 0.0f;
#pragma unroll
    for (int i = 0; i < NSTRIPE; ++i) sum += p[i * BUCKET_NODES];
    out[n] = sum;
}

// ---------------- Fallback: atomic kernel (if ws too small) ---------------
__global__ void fallback_atomic_kernel(const float* __restrict__ edge_eng,
                                       const int*   __restrict__ edge_center,
                                       const int*   __restrict__ edge_neighbor,
                                       const int*   __restrict__ species,
                                       const float* __restrict__ scales,
                                       float*       __restrict__ out, int n_edges)
{
    __shared__ float s_scale[16];
    if (threadIdx.x < 16) s_scale[threadIdx.x] = scales[threadIdx.x] * 0.125f;
    __syncthreads();
    const int stride = gridDim.x * blockDim.x;
    for (int i = blockIdx.x * blockDim.x + threadIdx.x; i < n_edges; i += stride) {
        const int c  = edge_center[i];
        const int cs = species[c];
        const int ns = species[edge_neighbor[i]];
        atomicAdd(&out[c], edge_eng[i] * s_scale[(cs << 2) | ns]);
    }
}

extern "C" void kernel_launch(void* const* d_in, const int* in_sizes, int n_in,
                              void* d_out, int out_size, void* d_ws, size_t ws_size,
                              hipStream_t stream) {
    const float* edge_eng   = (const float*)d_in[0];
    const int*   edge_index = (const int*)  d_in[1];
    const int*   species    = (const int*)  d_in[2];
    const float* scales     = (const float*)d_in[3];
    float*       out        = (float*)      d_out;

    const int n_edges = in_sizes[1] / 2;
    const int n_nodes = in_sizes[2];
    const int* edge_center   = edge_index;
    const int* edge_neighbor = edge_index + n_edges;

    const int nb      = (n_nodes + BUCKET_NODES - 1) >> BUCKET_SHIFT;
    const int n_words = (n_nodes + 15) / 16;
    const int n_cnt   = nb * NSTRIPE;

    // ws layout: [counters: 4096 pad][packed species][pairs][partials]
    const size_t off_counters = 0;
    const size_t off_packed   = 4096;
    const size_t off_pairs    = (off_packed + (size_t)n_words * 4 + 255) & ~(size_t)255;
    const size_t off_partials = off_pairs + (size_t)n_cnt * CAP8 * sizeof(int2);
    const size_t needed       = off_partials + (size_t)n_cnt * BUCKET_NODES * sizeof(float);

    if (nb > MAX_NB || n_words > MAX_SP_WORDS || (size_t)n_cnt * 4 > off_packed ||
        ws_size < needed) {
        hipMemsetAsync(d_out, 0, (size_t)out_size * sizeof(float), stream);
        int grid = (n_edges + 255) / 256;
        if (grid > 2048) grid = 2048;
        fallback_atomic_kernel<<<grid, 256, 0, stream>>>(
            edge_eng, edge_center, edge_neighbor, species, scales, out, n_edges);
        return;
    }

    int*          counters = (int*)         ((char*)d_ws + off_counters);
    unsigned int* packed   = (unsigned int*)((char*)d_ws + off_packed);
    int2*         pairs    = (int2*)        ((char*)d_ws + off_pairs);
    float*        partials = (float*)       ((char*)d_ws + off_partials);

    const int k0_threads = (n_words > n_cnt ? n_words : n_cnt);
    k0_pack<<<(k0_threads + 255) / 256, 256, 0, stream>>>(
        species, packed, counters, n_nodes, n_words, n_cnt);

    const int k1_blocks = (n_edges + CHUNK - 1) / CHUNK;
    k1_scatter<<<k1_blocks, 256, 0, stream>>>(
        edge_eng, edge_center, edge_neighbor, packed, scales,
        pairs, counters, n_edges, nb, n_words);

    k2_accumulate<<<n_cnt, 256, 0, stream>>>(pairs, counters, partials);

    k3_reduce<<<(n_nodes + 255) / 256, 256, 0, stream>>>(partials, out, n_nodes);
}

// Round 7
// 101.357 us; speedup vs baseline: 3.3940x; 1.1784x over previous
//
#include <hip/hip_runtime.h>

// EdgewiseEnergySum:
//   out[n] = 0.125 * sum_{e : center(e)==n} edge_eng[e] * scales[sp[center(e)], sp[neighbor(e)]]
//
// R1: 6.4M device atomics -> 344 us (memory-side atomic throttle, 32B/atomic).
// R2: bucket counting-sort -> 162 us (K1 latency-bound, occ 21%).
// R3: species 2-bit LDS table + int4 loads -> 120 us (K1 95 us, occ 37%).
// R4/R6: K1 single-pass (16 edges/thread in regs) + striped counters
//        -> 119 us (K1 77 us, occ 50%, VALU 7.5%, FETCH 38 MB).
//        Occupancy capped by 27 KB LDS per 256-thread block (~5 blocks/CU).
// R7: 512-thread K1 blocks -> 8 waves share one 25 KB species table;
//     4 blocks x 27 KB = 108 KB <= 160 KB, 32 waves/CU possible.
//     K2 reads vectorized (int4 = 2 pairs).

#define BUCKET_SHIFT 10
#define BUCKET_NODES 1024
#define MAX_NB       128
#define NSTRIPE      8
#define CAP8         8960             // per-(bucket,stripe): mean 8163 + ~8.8 sigma
#define K1_THREADS   512
#define T_EDGES      16               // edges per thread
#define CHUNK        8192             // 512 threads * 16 edges
#define MAX_SP_WORDS 6272             // 2-bit species, 16/word: up to 100352 nodes (25 KB)

// ---------------- K0: pack species 2-bit + zero counters ------------------
__global__ void k0_pack(const int* __restrict__ species,
                        unsigned int* __restrict__ packed,
                        int* __restrict__ counters,
                        int n_nodes, int n_words, int n_cnt)
{
    const int w = blockIdx.x * blockDim.x + threadIdx.x;
    if (w < n_cnt) counters[w] = 0;
    if (w >= n_words) return;
    const int base = w * 16;
    unsigned int v = 0;
    if (base + 16 <= n_nodes) {
#pragma unroll
        for (int q = 0; q < 4; ++q) {
            const int4 s4 = *(const int4*)(species + base + 4 * q);
            v |= (unsigned int)(s4.x & 3) << (8 * q + 0);
            v |= (unsigned int)(s4.y & 3) << (8 * q + 2);
            v |= (unsigned int)(s4.z & 3) << (8 * q + 4);
            v |= (unsigned int)(s4.w & 3) << (8 * q + 6);
        }
    } else {
        const int m = n_nodes - base;
        for (int j = 0; j < m; ++j)
            v |= (unsigned int)(species[base + j] & 3) << (2 * j);
    }
    packed[w] = v;
}

// ---------------- K1: reg-resident histogram + alloc + scatter ------------
__global__ void __launch_bounds__(K1_THREADS)
k1_scatter(const float* __restrict__ edge_eng,
           const int*   __restrict__ edge_center,
           const int*   __restrict__ edge_neighbor,
           const unsigned int* __restrict__ sp_packed,
           const float* __restrict__ scales,
           int2*        __restrict__ pairs,     // [NB*NSTRIPE][CAP8]
           int*         __restrict__ counters,  // [NB*NSTRIPE], zeroed by k0
           int n_edges, int nb, int n_sp_words)
{
    __shared__ unsigned int s_sp[MAX_SP_WORDS];  // 25 KB shared by 8 waves
    __shared__ float s_scale[16];
    __shared__ int hist[MAX_NB];
    __shared__ int rbase[MAX_NB];
    __shared__ int cursor[MAX_NB];

    const int tid = threadIdx.x;
    if (tid < 16) s_scale[tid] = scales[tid] * 0.125f;   // fold 1/sqrt(64)
    for (int i = tid; i < n_sp_words; i += K1_THREADS) s_sp[i] = sp_packed[i];
    for (int b = tid; b < nb; b += K1_THREADS) hist[b] = 0;
    __syncthreads();

    const int lo     = blockIdx.x * CHUNK;
    const int stripe = blockIdx.x & (NSTRIPE - 1);

    // ---- Load this thread's 16 edges ONCE into registers -----------------
    int4   c4[4];
    int4   n4[4];
    float4 e4[4];
    const bool full = ((n_edges & 3) == 0) && (lo + CHUNK <= n_edges);
    if (full) {
#pragma unroll
        for (int k = 0; k < 4; ++k) {
            const int idx = lo + 4 * tid + (4 * K1_THREADS) * k;
            c4[k] = *(const int4*)  (edge_center   + idx);
            n4[k] = *(const int4*)  (edge_neighbor + idx);
            e4[k] = *(const float4*)(edge_eng      + idx);
        }
    } else {
#pragma unroll
        for (int k = 0; k < 4; ++k) {
            const int idx = lo + 4 * tid + (4 * K1_THREADS) * k;
            int*   cp = (int*)  &c4[k];
            int*   np = (int*)  &n4[k];
            float* ep = (float*)&e4[k];
#pragma unroll
            for (int j = 0; j < 4; ++j) {
                const int i = idx + j;
                if (i < n_edges) { cp[j] = edge_center[i]; np[j] = edge_neighbor[i]; ep[j] = edge_eng[i]; }
                else             { cp[j] = -1; np[j] = 0; ep[j] = 0.0f; }
            }
        }
    }

    // ---- Phase A: histogram from registers -------------------------------
#pragma unroll
    for (int k = 0; k < 4; ++k) {
        const int* cp = (const int*)&c4[k];
#pragma unroll
        for (int j = 0; j < 4; ++j)
            if (cp[j] >= 0) atomicAdd(&hist[cp[j] >> BUCKET_SHIFT], 1);
    }
    __syncthreads();

    // ---- Phase B: reserve ranges in this block's stripe ------------------
    for (int b = tid; b < nb; b += K1_THREADS) {
        const int c = hist[b];
        rbase[b]  = c ? atomicAdd(&counters[(b << 3) | stripe], c) : 0;
        cursor[b] = 0;
    }
    __syncthreads();

    // ---- Phase C: scatter from registers (no global loads) ---------------
#define SP(n) ((s_sp[(unsigned)(n) >> 4] >> (((n) & 15) << 1)) & 3)
#pragma unroll
    for (int k = 0; k < 4; ++k) {
        const int*   cp = (const int*)  &c4[k];
        const int*   np = (const int*)  &n4[k];
        const float* ep = (const float*)&e4[k];
#pragma unroll
        for (int j = 0; j < 4; ++j) {
            const int c = cp[j];
            if (c < 0) continue;
            const int   b = c >> BUCKET_SHIFT;
            const float v = ep[j] * s_scale[(SP(c) << 2) | SP(np[j])];
            const int   r = atomicAdd(&cursor[b], 1);         // LDS atomic
            const int pos = rbase[b] + r;
            if (pos < CAP8)                                    // ~8-sigma guard
                pairs[(size_t)((b << 3) | stripe) * CAP8 + pos] =
                    make_int2(c, __float_as_int(v));
        }
    }
#undef SP
}

// ---------------- K2: per-(bucket,stripe) LDS accumulation ----------------
__global__ void k2_accumulate(const int2* __restrict__ pairs,
                              const int*  __restrict__ counters,
                              float*      __restrict__ partials) // [NB*NSTRIPE][1024]
{
    __shared__ float acc[BUCKET_NODES];
    const int bs  = blockIdx.x;                // (b<<3)|s
    const int tid = threadIdx.x;

    for (int i = tid; i < BUCKET_NODES; i += blockDim.x) acc[i] = 0.0f;
    __syncthreads();

    const int count = min(counters[bs], CAP8);
    const int2* p = pairs + (size_t)bs * CAP8;

    // Vectorized: 2 pairs (int4) per thread per iteration.
    for (int i = 2 * tid; i + 2 <= count; i += 2 * blockDim.x) {
        const int4 two = *(const int4*)(p + i);
        atomicAdd(&acc[two.x & (BUCKET_NODES - 1)], __int_as_float(two.y));
        atomicAdd(&acc[two.z & (BUCKET_NODES - 1)], __int_as_float(two.w));
    }
    if ((count & 1) && tid == 0) {
        const int2 e = p[count - 1];
        atomicAdd(&acc[e.x & (BUCKET_NODES - 1)], __int_as_float(e.y));
    }
    __syncthreads();

    float* dst = partials + (size_t)bs * BUCKET_NODES;
    for (int i = tid; i < BUCKET_NODES; i += blockDim.x) dst[i] = acc[i];
}

// ---------------- K3: reduce NSTRIPE partials, plain store ----------------
__global__ void k3_reduce(const float* __restrict__ partials,
                          float*       __restrict__ out, int n_nodes)
{
    const int n = blockIdx.x * blockDim.x + threadIdx.x;
    if (n >= n_nodes) return;
    const int b     = n >> BUCKET_SHIFT;
    const int local = n & (BUCKET_NODES - 1);
    const float* p  = partials + (size_t)b * NSTRIPE * BUCKET_NODES + local;
    float sum = 0.0f;
#pragma unroll
    for (int i = 0; i < NSTRIPE; ++i) sum += p[i * BUCKET_NODES];
    out[n] = sum;
}

// ---------------- Fallback: atomic kernel (if ws too small) ---------------
__global__ void fallback_atomic_kernel(const float* __restrict__ edge_eng,
                                       const int*   __restrict__ edge_center,
                                       const int*   __restrict__ edge_neighbor,
                                       const int*   __restrict__ species,
                                       const float* __restrict__ scales,
                                       float*       __restrict__ out, int n_edges)
{
    __shared__ float s_scale[16];
    if (threadIdx.x < 16) s_scale[threadIdx.x] = scales[threadIdx.x] * 0.125f;
    __syncthreads();
    const int stride = gridDim.x * blockDim.x;
    for (int i = blockIdx.x * blockDim.x + threadIdx.x; i < n_edges; i += stride) {
        const int c  = edge_center[i];
        const int cs = species[c];
        const int ns = species[edge_neighbor[i]];
        atomicAdd(&out[c], edge_eng[i] * s_scale[(cs << 2) | ns]);
    }
}

extern "C" void kernel_launch(void* const* d_in, const int* in_sizes, int n_in,
                              void* d_out, int out_size, void* d_ws, size_t ws_size,
                              hipStream_t stream) {
    const float* edge_eng   = (const float*)d_in[0];
    const int*   edge_index = (const int*)  d_in[1];
    const int*   species    = (const int*)  d_in[2];
    const float* scales     = (const float*)d_in[3];
    float*       out        = (float*)      d_out;

    const int n_edges = in_sizes[1] / 2;
    const int n_nodes = in_sizes[2];
    const int* edge_center   = edge_index;
    const int* edge_neighbor = edge_index + n_edges;

    const int nb      = (n_nodes + BUCKET_NODES - 1) >> BUCKET_SHIFT;
    const int n_words = (n_nodes + 15) / 16;
    const int n_cnt   = nb * NSTRIPE;

    // ws layout: [counters: 4096 pad][packed species][pairs][partials]
    const size_t off_counters = 0;
    const size_t off_packed   = 4096;
    const size_t off_pairs    = (off_packed + (size_t)n_words * 4 + 255) & ~(size_t)255;
    const size_t off_partials = off_pairs + (size_t)n_cnt * CAP8 * sizeof(int2);
    const size_t needed       = off_partials + (size_t)n_cnt * BUCKET_NODES * sizeof(float);

    if (nb > MAX_NB || n_words > MAX_SP_WORDS || (size_t)n_cnt * 4 > off_packed ||
        ws_size < needed) {
        hipMemsetAsync(d_out, 0, (size_t)out_size * sizeof(float), stream);
        int grid = (n_edges + 255) / 256;
        if (grid > 2048) grid = 2048;
        fallback_atomic_kernel<<<grid, 256, 0, stream>>>(
            edge_eng, edge_center, edge_neighbor, species, scales, out, n_edges);
        return;
    }

    int*          counters = (int*)         ((char*)d_ws + off_counters);
    unsigned int* packed   = (unsigned int*)((char*)d_ws + off_packed);
    int2*         pairs    = (int2*)        ((char*)d_ws + off_pairs);
    float*        partials = (float*)       ((char*)d_ws + off_partials);

    const int k0_threads = (n_words > n_cnt ? n_words : n_cnt);
    k0_pack<<<(k0_threads + 255) / 256, 256, 0, stream>>>(
        species, packed, counters, n_nodes, n_words, n_cnt);

    const int k1_blocks = (n_edges + CHUNK - 1) / CHUNK;
    k1_scatter<<<k1_blocks, K1_THREADS, 0, stream>>>(
        edge_eng, edge_center, edge_neighbor, packed, scales,
        pairs, counters, n_edges, nb, n_words);

    k2_accumulate<<<n_cnt, 256, 0, stream>>>(pairs, counters, partials);

    k3_reduce<<<(n_nodes + 255) / 256, 256, 0, stream>>>(partials, out, n_nodes);
}